// Round 9
// baseline (41.753 us; speedup 1.0000x reference)
//
#include <hip/hip_runtime.h>

// LIF scan, x (B=32,G=4,T=512,C=256) f32 -> 32768 chains, T sequential.
// Memory-bound: 67 MB R + 67 MB W.
//
// R9 = R7's read bursts + R6's 1 KiB x4 write bursts, single barrier/window.
//  - Block = sequence n (256 threads, 4 waves), 128 blocks.
//  - Reads: 16 KiB contiguous window bursts via 4x global_load_lds_dwordx4
//    per wave, triple-buffered (48 KiB), 2 windows ahead, counted vmcnt.
//  - Compute: 16 steps; xt via ds_read_b32 (conflict-free); Vm in registers;
//    Vm staged to DOUBLE-buffered obuf (stride-1 ds_write, conflict-free).
//  - Stores: after the window barrier, wave wv stores rows 4i+wv as ONE
//    contiguous 1 KiB nontemporal global_store_dwordx4 each (ds_read_b128,
//    conflict-free). Double buffer -> stores(W) overlap compute(W+1), no
//    second barrier (R8's mistake).
//  - One combined wait per window: lgkmcnt(0) + vmcnt(N) + s_barrier.
//    vmcnt counts exact (in-order retirement): steady state 8.
//  - Recurrence bit-exact: contract off, v=(w*xt)+(a*Vm); Vm'=(Vm>=1)?0:v.

typedef float f32x4 __attribute__((ext_vector_type(4)));

constexpr int T_STEPS = 512;
constexpr int CCH     = 256;
constexpr int NSEQ    = 128;
constexpr int WIN     = 16;
constexpr int NWIN    = T_STEPS / WIN;   // 32

__device__ __forceinline__ void sfence() { __builtin_amdgcn_sched_barrier(0); }

__global__ __launch_bounds__(256, 1) void lif_kernel(
    const float* __restrict__ x,
    const float* __restrict__ w_input,
    const float* __restrict__ w_leak,
    float* __restrict__ out)
{
#pragma clang fp contract(off)
    __shared__ float xw[3][WIN * CCH];     // 3 x 16 KiB x-windows
    __shared__ float obuf[2][WIN * CCH];   // 2 x 16 KiB out staging

    const int tid = threadIdx.x;
    const int wv  = tid >> 6;
    const int l   = tid & 63;
    const int n   = blockIdx.x;

    const float w = w_input[tid];
    const float a = 1.0f - w_leak[tid];

    const float* xg = x   + (size_t)n * T_STEPS * CCH;
    float*       og = out + (size_t)n * T_STEPS * CCH;

    // 16 KiB read burst for window Wt into buffer Wt%3 (linear identity map:
    // wave wv, instr i, lane l <-> byte wv*1024 + i*4096 + l*16 on both sides)
    auto issue = [&](int Wt) {
        float* dst0 = &xw[Wt % 3][wv * 256];
        const float* src0 = xg + (size_t)Wt * (WIN * CCH) + tid * 4;
#pragma unroll
        for (int i = 0; i < 4; ++i) {
            __builtin_amdgcn_global_load_lds(
                (const __attribute__((address_space(1))) void*)(src0 + i * 1024),
                (__attribute__((address_space(3))) void*)(dst0 + i * 1024),
                16, 0, 0);
        }
        sfence();
    };

    float Vm = 0.0f;

    auto compute = [&](int Wt) {
        const float* xb = &xw[Wt % 3][0];
        float* ob = &obuf[Wt & 1][0];
#pragma unroll
        for (int k = 0; k < WIN; ++k) {
            const float xt = xb[k * CCH + tid];
            // exact numpy op order: mul, mul, add (no FMA), then spike gate
            const float v = (w * xt) + (a * Vm);
            Vm = (Vm - 1.0f >= 0.0f) ? 0.0f : v;
            ob[k * CCH + tid] = Vm;
        }
        sfence();
    };

    // Write burst: wave wv stores rows 4i+wv (i=0..3) of window Wt, each one
    // contiguous 1 KiB nontemporal dwordx4 (ds_read_b128 src, conflict-free).
    auto stores = [&](int Wt) {
        const float* ob = &obuf[Wt & 1][0];
#pragma unroll
        for (int i = 0; i < 4; ++i) {
            const int r = 4 * i + wv;
            const f32x4 vv = *(const f32x4*)&ob[r * CCH + 4 * l];
            __builtin_nontemporal_store(
                vv, (f32x4*)(og + (size_t)(Wt * WIN + r) * CCH + 4 * l));
        }
        sfence();
    };

    // Combined per-window wait: own LDS ops drained (obuf writes + store
    // reads), x[next] loads landed, then block-wide barrier.
    auto window_wait = [&](int vm) {
        sfence();
        asm volatile("s_waitcnt lgkmcnt(0)" ::: "memory");
        if (vm == 4)  asm volatile("s_waitcnt vmcnt(4)" ::: "memory");
        if (vm == 8)  asm volatile("s_waitcnt vmcnt(8)" ::: "memory");
        __builtin_amdgcn_s_barrier();
        sfence();
    };

    // Prologue: x[0], x[1] in flight; x[0] complete before compute(0).
    issue(0); issue(1);
    asm volatile("s_waitcnt vmcnt(4)" ::: "memory");   // x[0] done (x[1] behind)
    __builtin_amdgcn_s_barrier();

    // W=0: after x[1]'s loads: issue(2) 4 -> vmcnt(4)
    issue(2);
    compute(0);
    window_wait(4);
    stores(0);

    // W=1..29 steady: after x[W+1]: stores(W-1) 4 + issue(W+2) 4 = 8
    for (int W = 1; W <= NWIN - 3; ++W) {
        issue(W + 2);
        compute(W);
        window_wait(8);
        stores(W);
    }

    // W=30: no issue; after x[31]: stores(29) 4 -> vmcnt(4)
    compute(NWIN - 2);
    window_wait(4);
    stores(NWIN - 2);

    // W=31: all x resident; just drain own LDS before reuse-free finish
    compute(NWIN - 1);
    sfence();
    asm volatile("s_waitcnt lgkmcnt(0)" ::: "memory");
    __builtin_amdgcn_s_barrier();
    sfence();
    stores(NWIN - 1);
}

extern "C" void kernel_launch(void* const* d_in, const int* in_sizes, int n_in,
                              void* d_out, int out_size, void* d_ws, size_t ws_size,
                              hipStream_t stream) {
    const float* x       = (const float*)d_in[0];
    const float* w_input = (const float*)d_in[1];
    const float* w_leak  = (const float*)d_in[2];
    float* out = (float*)d_out;

    dim3 grid(NSEQ);        // 128 blocks, block n = sequence n
    dim3 block(CCH);        // 256 threads = 4 waves
    hipLaunchKernelGGL(lif_kernel, grid, block, 0, stream,
                       x, w_input, w_leak, out);
}

// Round 10
// 34.997 us; speedup vs baseline: 1.1930x; 1.1930x over previous
//
#include <hip/hip_runtime.h>

// LIF scan, x (B=32,G=4,T=512,C=256) f32 -> 32768 chains, T sequential.
// Memory-bound: 67 MB R + 67 MB W.
//
// R10: lane = 4 consecutive channels (f32x4); wave = full 256-channel row.
//  - EVERY load/store instruction is one contiguous 1 KiB row. No LDS, no
//    barriers, no transpose, 128 free-running waves (the R3/R7 evidence:
//    free-running >> barrier-paced; contiguity per instr is the lever).
//  - 32-row register ring (f32x4 buf[32], statically indexed), refilled in
//    8-row chunks: 8 loads (8 KiB burst) -> 8 compute steps (4 independent
//    Vm chains/lane) -> 8 stores (8 KiB burst). R7's burst alternation at
//    4x coarser granularity, stores never behind a wait.
//  - Consume distance ~56 vmem ops < vmcnt cap 63: compiler waits stay exact.
//  - Recurrence bit-exact: contract off, v=(w*xt)+(a*Vm); Vm'=(Vm-1>=0)?0:v.

typedef float f32x4 __attribute__((ext_vector_type(4)));

constexpr int T_STEPS = 512;
constexpr int CCH     = 256;
constexpr int NSEQ    = 128;
constexpr int ROWS    = 32;              // ring depth (rows) = 4 chunks of 8
constexpr int NIT     = T_STEPS / ROWS;  // 16 outer iterations

__device__ __forceinline__ void sfence() { __builtin_amdgcn_sched_barrier(0); }

__device__ __forceinline__ float stepf(float xt, float w, float a, float& Vm) {
    const float v = (w * xt) + (a * Vm);          // mul, mul, add (no FMA)
    Vm = (Vm - 1.0f >= 0.0f) ? 0.0f : v;          // spike gate, exact
    return Vm;
}

__global__ __launch_bounds__(64, 1) void lif_kernel(
    const float* __restrict__ x,
    const float* __restrict__ w_input,
    const float* __restrict__ w_leak,
    float* __restrict__ out)
{
#pragma clang fp contract(off)
    const int l = threadIdx.x;
    const int n = blockIdx.x;

    const size_t base = (size_t)n * T_STEPS * CCH + 4 * l;
    const float* xg = x   + base;    // 16B-aligned
    float*       og = out + base;

    const f32x4 w4 = *(const f32x4*)(w_input + 4 * l);
    const f32x4 l4 = *(const f32x4*)(w_leak  + 4 * l);
    const float w0 = w4.x, w1 = w4.y, w2 = w4.z, w3 = w4.w;
    const float a0 = 1.0f - l4.x, a1 = 1.0f - l4.y,
                a2 = 1.0f - l4.z, a3 = 1.0f - l4.w;

    // Prime the ring: rows 0..31 (32 KiB in flight per wave)
    f32x4 buf[ROWS];
#pragma unroll
    for (int r = 0; r < ROWS; ++r)
        buf[r] = *(const f32x4*)(xg + (size_t)r * CCH);

    float Vm0 = 0.0f, Vm1 = 0.0f, Vm2 = 0.0f, Vm3 = 0.0f;

    for (int W = 0; W < NIT; ++W) {
        const int tb = W * ROWS;
#pragma unroll
        for (int cc = 0; cc < 4; ++cc) {          // 4 chunks of 8 rows
            // grab current chunk from the ring
            f32x4 xt[8];
#pragma unroll
            for (int j = 0; j < 8; ++j) xt[j] = buf[cc * 8 + j];
            sfence();

            // 8 KiB read burst: refill this chunk's slots for window W+1
            if (W + 1 < NIT) {
#pragma unroll
                for (int j = 0; j < 8; ++j)
                    buf[cc * 8 + j] =
                        *(const f32x4*)(xg + (size_t)(tb + ROWS + cc * 8 + j) * CCH);
            }
            sfence();

            // 8 compute steps, 4 independent chains (pure VALU, high ILP)
            f32x4 sv[8];
#pragma unroll
            for (int j = 0; j < 8; ++j) {
                sv[j].x = stepf(xt[j].x, w0, a0, Vm0);
                sv[j].y = stepf(xt[j].y, w1, a1, Vm1);
                sv[j].z = stepf(xt[j].z, w2, a2, Vm2);
                sv[j].w = stepf(xt[j].w, w3, a3, Vm3);
            }
            sfence();

            // 8 KiB write burst: one contiguous 1 KiB row per instruction
#pragma unroll
            for (int j = 0; j < 8; ++j)
                *(f32x4*)(og + (size_t)(tb + cc * 8 + j) * CCH) = sv[j];
            sfence();
        }
    }
}

extern "C" void kernel_launch(void* const* d_in, const int* in_sizes, int n_in,
                              void* d_out, int out_size, void* d_ws, size_t ws_size,
                              hipStream_t stream) {
    const float* x       = (const float*)d_in[0];
    const float* w_input = (const float*)d_in[1];
    const float* w_leak  = (const float*)d_in[2];
    float* out = (float*)d_out;

    dim3 grid(NSEQ);       // 128 blocks, block n = sequence n
    dim3 block(64);        // 1 wave: 64 lanes x 4 channels = 256 channels
    hipLaunchKernelGGL(lif_kernel, grid, block, 0, stream,
                       x, w_input, w_leak, out);
}

// Round 11
// 28.602 us; speedup vs baseline: 1.4598x; 1.2236x over previous
//
#include <hip/hip_runtime.h>

// LIF scan, x (B=32,G=4,T=512,C=256) f32 -> 32768 chains, T sequential.
// Memory-bound: 67 MB R + 67 MB W.
//
// R11 = R10's free-running reg-ring burst structure, spread over ALL 256 CUs.
//  - Lane = 2 consecutive channels (f32x2). Block = one 128-channel half of
//    one sequence -> 256 blocks x 1 wave = 1 block per CU (R10 used only 128
//    CUs; per-CU BW ~29-36 GB/s is the measured binding resource; chip copy
//    ceiling = 25 GB/s/CU across 256 CUs).
//  - Every load/store instr = 512 B contiguous (4 cachelines). No LDS, no
//    barriers, free-running waves (R8/R9 showed barrier pacing loses).
//  - 32-row register ring (f32x2 buf[32], statically indexed), 8-row chunks:
//    8 loads (4 KiB burst) -> 8 steps x 2 chains -> 8 stores (4 KiB burst).
//    Consume distance 56 vmem ops < vmcnt cap 63: compiler waits stay exact.
//  - Half-pair swizzle: n = b&127, h = b>>7 -> both halves of sequence n land
//    on the same XCD.
//  - Recurrence bit-exact: contract off, v=(w*xt)+(a*Vm); Vm'=(Vm-1>=0)?0:v.

typedef float f32x2 __attribute__((ext_vector_type(2)));

constexpr int T_STEPS = 512;
constexpr int CCH     = 256;
constexpr int ROWS    = 32;              // ring depth (rows) = 4 chunks of 8
constexpr int NIT     = T_STEPS / ROWS;  // 16 outer iterations

__device__ __forceinline__ void sfence() { __builtin_amdgcn_sched_barrier(0); }

__device__ __forceinline__ float stepf(float xt, float w, float a, float& Vm) {
    const float v = (w * xt) + (a * Vm);          // mul, mul, add (no FMA)
    Vm = (Vm - 1.0f >= 0.0f) ? 0.0f : v;          // spike gate, exact
    return Vm;
}

__global__ __launch_bounds__(64, 1) void lif_kernel(
    const float* __restrict__ x,
    const float* __restrict__ w_input,
    const float* __restrict__ w_leak,
    float* __restrict__ out)
{
#pragma clang fp contract(off)
    const int l = threadIdx.x;
    const int b = blockIdx.x;
    const int n = b & 127;               // sequence
    const int h = b >> 7;                // channel half (0/1)

    const int ch0 = h * 128 + 2 * l;     // this lane's first channel
    const size_t base = (size_t)n * T_STEPS * CCH + ch0;
    const float* xg = x   + base;        // 8B-aligned
    float*       og = out + base;

    const f32x2 w2 = *(const f32x2*)(w_input + ch0);
    const f32x2 l2 = *(const f32x2*)(w_leak  + ch0);
    const float w0 = w2.x, w1 = w2.y;
    const float a0 = 1.0f - l2.x, a1 = 1.0f - l2.y;

    // Prime the ring: rows 0..31 (16 KiB in flight per wave)
    f32x2 buf[ROWS];
#pragma unroll
    for (int r = 0; r < ROWS; ++r)
        buf[r] = *(const f32x2*)(xg + (size_t)r * CCH);

    float Vm0 = 0.0f, Vm1 = 0.0f;

    for (int W = 0; W < NIT; ++W) {
        const int tb = W * ROWS;
#pragma unroll
        for (int cc = 0; cc < 4; ++cc) {          // 4 chunks of 8 rows
            // grab current chunk from the ring
            f32x2 xt[8];
#pragma unroll
            for (int j = 0; j < 8; ++j) xt[j] = buf[cc * 8 + j];
            sfence();

            // 4 KiB read burst: refill this chunk's slots for window W+1
            if (W + 1 < NIT) {
#pragma unroll
                for (int j = 0; j < 8; ++j)
                    buf[cc * 8 + j] =
                        *(const f32x2*)(xg + (size_t)(tb + ROWS + cc * 8 + j) * CCH);
            }
            sfence();

            // 8 compute steps, 2 independent chains (pure VALU)
            f32x2 sv[8];
#pragma unroll
            for (int j = 0; j < 8; ++j) {
                sv[j].x = stepf(xt[j].x, w0, a0, Vm0);
                sv[j].y = stepf(xt[j].y, w1, a1, Vm1);
            }
            sfence();

            // 4 KiB write burst: one contiguous 512 B run per instruction
#pragma unroll
            for (int j = 0; j < 8; ++j)
                *(f32x2*)(og + (size_t)(tb + cc * 8 + j) * CCH) = sv[j];
            sfence();
        }
    }
}

extern "C" void kernel_launch(void* const* d_in, const int* in_sizes, int n_in,
                              void* d_out, int out_size, void* d_ws, size_t ws_size,
                              hipStream_t stream) {
    const float* x       = (const float*)d_in[0];
    const float* w_input = (const float*)d_in[1];
    const float* w_leak  = (const float*)d_in[2];
    float* out = (float*)d_out;

    dim3 grid(256);        // 1 block per CU: 128 sequences x 2 channel-halves
    dim3 block(64);        // 1 wave: 64 lanes x 2 channels = 128 channels
    hipLaunchKernelGGL(lif_kernel, grid, block, 0, stream,
                       x, w_input, w_leak, out);
}

// Round 12
// 27.039 us; speedup vs baseline: 1.5442x; 1.0578x over previous
//
#include <hip/hip_runtime.h>

// LIF scan, x (B=32,G=4,T=512,C=256) f32 -> 32768 chains, T sequential.
// Memory-bound: 67 MB R + 67 MB W.
//
// R12: max TLP + free-running + burst chunks (the untested grid cell).
//  - 512 blocks x 64 threads: lane = 1 channel, block = 64-channel quarter
//    of one sequence -> 512 waves = 2 waves/CU. Waves cover each other's
//    chunk-boundary stalls (R11 had 1/CU: every stall = idle CU).
//  - Free-running: no LDS, no barriers (R8/R9: barrier pacing always lost).
//  - 32-row register ring, 8-row chunks: 8 scalar loads (256 B/instr burst)
//    -> 8 steps -> 8 scalar stores (256 B/instr burst). Consume distance
//    48 vmem ops < vmcnt cap 63: compiler-inserted waits stay exact.
//  - XCD swizzle (from R3's winning bundle): the 4 quarters of sequence n
//    land on XCD n%8 -> reads/writes of one row arrive from one XCD's L2.
//  - Recurrence bit-exact: contract off, v=(w*xt)+(a*Vm); Vm'=(Vm-1>=0)?0:v.

constexpr int T_STEPS = 512;
constexpr int CCH     = 256;
constexpr int ROWS    = 32;              // ring depth = 4 chunks of 8
constexpr int NIT     = T_STEPS / ROWS;  // 16 outer iterations

__device__ __forceinline__ void sfence() { __builtin_amdgcn_sched_barrier(0); }

__global__ __launch_bounds__(64, 2) void lif_kernel(
    const float* __restrict__ x,
    const float* __restrict__ w_input,
    const float* __restrict__ w_leak,
    float* __restrict__ out)
{
#pragma clang fp contract(off)
    const int l = threadIdx.x;
    const int b = blockIdx.x;
    // swizzle: b = (n%8) + 8*(4*(n/8) + q)  ->  XCD(b%8) == n%8
    const int n = (b & 7) + ((b >> 5) << 3);
    const int q = (b >> 3) & 3;

    const int ch = q * 64 + l;           // this lane's channel
    const size_t base = (size_t)n * T_STEPS * CCH + ch;
    const float* xg = x   + base;
    float*       og = out + base;

    const float w = w_input[ch];
    const float a = 1.0f - w_leak[ch];

    // Prime the ring: rows 0..31 (8 KiB in flight per wave)
    float buf[ROWS];
#pragma unroll
    for (int r = 0; r < ROWS; ++r)
        buf[r] = xg[(size_t)r * CCH];

    float Vm = 0.0f;

    for (int W = 0; W < NIT; ++W) {
        const int tb = W * ROWS;
#pragma unroll
        for (int cc = 0; cc < 4; ++cc) {          // 4 chunks of 8 rows
            // grab current chunk from the ring
            float xt[8];
#pragma unroll
            for (int j = 0; j < 8; ++j) xt[j] = buf[cc * 8 + j];
            sfence();

            // read burst: refill this chunk's slots for window W+1
            if (W + 1 < NIT) {
#pragma unroll
                for (int j = 0; j < 8; ++j)
                    buf[cc * 8 + j] = xg[(size_t)(tb + ROWS + cc * 8 + j) * CCH];
            }
            sfence();

            // 8 compute steps (serial dependent chain)
            float sv[8];
#pragma unroll
            for (int j = 0; j < 8; ++j) {
                const float v = (w * xt[j]) + (a * Vm);   // mul, mul, add
                Vm = (Vm - 1.0f >= 0.0f) ? 0.0f : v;      // spike gate
                sv[j] = Vm;
            }
            sfence();

            // write burst: 8 back-to-back 256 B store instructions
#pragma unroll
            for (int j = 0; j < 8; ++j)
                og[(size_t)(tb + cc * 8 + j) * CCH] = sv[j];
            sfence();
        }
    }
}

extern "C" void kernel_launch(void* const* d_in, const int* in_sizes, int n_in,
                              void* d_out, int out_size, void* d_ws, size_t ws_size,
                              hipStream_t stream) {
    const float* x       = (const float*)d_in[0];
    const float* w_input = (const float*)d_in[1];
    const float* w_leak  = (const float*)d_in[2];
    float* out = (float*)d_out;

    dim3 grid(512);        // 2 waves per CU: 128 sequences x 4 quarters
    dim3 block(64);        // 1 wave: 64 lanes x 1 channel
    hipLaunchKernelGGL(lif_kernel, grid, block, 0, stream,
                       x, w_input, w_leak, out);
}

// Round 13
// 26.090 us; speedup vs baseline: 1.6003x; 1.0364x over previous
//
#include <hip/hip_runtime.h>

// LIF scan, x (B=32,G=4,T=512,C=256) f32 -> 32768 chains, T sequential.
// Memory-bound: 67 MB R + 67 MB W.
//
// R13: producer/consumer wave specialization (split load/store vmcnt queues).
//  Model from R3..R12 (all ~27-28us): loads+stores share the per-wave
//  63-outstanding-vmem cap -> at 2 vmem/step a wave runs ~31 steps ahead ->
//  chip in-flight reads ~2.6 MB -> ~2.4 TB/s read side (Little's law, ~1us
//  loaded latency). Splitting queues is the only way to deepen reads.
//  - Block = sequence n: 320 threads = 1 producer wave + 4 consumer waves.
//  - Producer: pure global_load_lds_dwordx4 (1 KiB contiguous row per instr)
//    into a K=4-window LDS ring (16 rows/window, 64 KiB). Counted vmcnt(32)
//    per window (W+1,W+2 stay in flight across barriers - T4 discipline).
//    Queue = loads only: 48 KiB in flight/block, 6 MB chip-wide (2.3x R12).
//  - Consumers: ch = wave*64+lane; scan from LDS (stride-1 ds_read,
//    conflict-free), free-running scalar stores (queue = stores only, never
//    waited). Barrier per window paces ring reuse only.
//  - Slot safety: window W+3 issued after barrier(W) into the slot consumers
//    finished at iter W-1; consumer reads of W are register-consumed before
//    barrier(W+1).
//  - Recurrence bit-exact: contract off, v=(w*xt)+(a*Vm); Vm'=(Vm-1>=0)?0:v.

constexpr int T_STEPS = 512;
constexpr int CCH     = 256;
constexpr int NSEQ    = 128;
constexpr int WIN     = 16;              // rows per window
constexpr int K       = 4;               // ring depth (windows)
constexpr int NW      = T_STEPS / WIN;   // 32

__device__ __forceinline__ void sfence() { __builtin_amdgcn_sched_barrier(0); }

__global__ __launch_bounds__(320, 1) void lif_kernel(
    const float* __restrict__ x,
    const float* __restrict__ w_input,
    const float* __restrict__ w_leak,
    float* __restrict__ out)
{
#pragma clang fp contract(off)
    __shared__ float xw[K][WIN * CCH];   // 4 x 16 KiB window ring

    const int tid  = threadIdx.x;
    const int wv   = tid >> 6;           // 0..3 consumers, 4 producer
    const int lane = tid & 63;
    const int n    = blockIdx.x;

    if (wv == 4) {
        // ---- producer wave: pure load queue ----
        const float* xg = x + (size_t)n * T_STEPS * CCH + lane * 4;
        auto issue = [&](int W) {
            const float* s0 = xg + (size_t)W * WIN * CCH;
            float* d0 = &xw[W & 3][0];
#pragma unroll
            for (int i = 0; i < WIN; ++i) {
                // one instr = one contiguous 1 KiB row t = W*16+i
                __builtin_amdgcn_global_load_lds(
                    (const __attribute__((address_space(1))) void*)(s0 + i * CCH),
                    (__attribute__((address_space(3))) void*)(d0 + i * CCH),
                    16, 0, 0);
            }
            sfence();
        };

        issue(0); issue(1); issue(2);    // 48 outstanding (< 63 cap)
        for (int W = 0; W < NW; ++W) {
            const int rem = NW - 1 - W;  // windows still outstanding after W
            if (rem >= 2)      asm volatile("s_waitcnt vmcnt(32)" ::: "memory");
            else if (rem == 1) asm volatile("s_waitcnt vmcnt(16)" ::: "memory");
            else               asm volatile("s_waitcnt vmcnt(0)"  ::: "memory");
            sfence();
            __builtin_amdgcn_s_barrier();   // window W now readable
            sfence();
            if (W + 3 < NW) issue(W + 3);   // into slot consumers freed at W-1
        }
    } else {
        // ---- consumer waves: scan + pure store queue ----
        const int ch = wv * 64 + lane;
        const float w = w_input[ch];
        const float a = 1.0f - w_leak[ch];
        float* og = out + (size_t)n * T_STEPS * CCH + ch;
        float Vm = 0.0f;

        for (int W = 0; W < NW; ++W) {
            sfence();
            __builtin_amdgcn_s_barrier();   // window W ready in LDS
            sfence();
            const float* xb = &xw[W & 3][0];
#pragma unroll
            for (int k = 0; k < WIN; ++k) {
                const float xt = xb[k * CCH + ch];       // stride-1, no conflict
                // exact numpy op order: mul, mul, add (no FMA), spike gate
                const float v = (w * xt) + (a * Vm);
                Vm = (Vm - 1.0f >= 0.0f) ? 0.0f : v;
                og[(size_t)(W * WIN + k) * CCH] = Vm;    // free-running store
            }
            sfence();
        }
    }
}

extern "C" void kernel_launch(void* const* d_in, const int* in_sizes, int n_in,
                              void* d_out, int out_size, void* d_ws, size_t ws_size,
                              hipStream_t stream) {
    const float* x       = (const float*)d_in[0];
    const float* w_input = (const float*)d_in[1];
    const float* w_leak  = (const float*)d_in[2];
    float* out = (float*)d_out;

    dim3 grid(NSEQ);       // 128 blocks, block n = sequence n
    dim3 block(320);       // 4 consumer waves + 1 producer wave
    hipLaunchKernelGGL(lif_kernel, grid, block, 0, stream,
                       x, w_input, w_leak, out);
}